// Round 1
// baseline (441.094 us; speedup 1.0000x reference)
//
#include <hip/hip_runtime.h>
#include <cstdint>
#include <cstddef>

// ArcFace FC: out[i][j] = S * (j==label[i] ? phi(cos_ij) : cos_ij)
// cos = normalize(x) @ normalize(W)^T,  B=512, D=512, C=100000

#define SSCALE 30.0f
#define COSM_  0.8775825618903728f
#define SINM_  0.4794255386042030f
#define TH_    (-0.8775825618903728f)
#define MM_    0.2397127693021015f
#define EPS_   1e-12f

typedef unsigned short ushort_t;
typedef __attribute__((ext_vector_type(8))) short bf16x8;
typedef __attribute__((ext_vector_type(4))) float f32x4;

__device__ inline ushort_t f2bf(float f) {
    union { float f; unsigned u; } x; x.f = f;
    unsigned r = (x.u + 0x7fffu + ((x.u >> 16) & 1u)) >> 16;
    return (ushort_t)r;
}

// ---------------- normalize rows (D=512 fixed), fp32 -> bf16 -----------------
// one wave per row; lane covers 8 consecutive floats
__global__ __launch_bounds__(256) void norm_rows_bf16(const float* __restrict__ in,
                                                      ushort_t* __restrict__ out,
                                                      int nrows) {
    int row = blockIdx.x * 4 + (threadIdx.x >> 6);
    if (row >= nrows) return;
    int lane = threadIdx.x & 63;
    const float4* p = (const float4*)(in + (size_t)row * 512);
    float4 a = p[2 * lane];
    float4 b = p[2 * lane + 1];
    float ss = a.x*a.x + a.y*a.y + a.z*a.z + a.w*a.w
             + b.x*b.x + b.y*b.y + b.z*b.z + b.w*b.w;
    #pragma unroll
    for (int off = 32; off > 0; off >>= 1) ss += __shfl_down(ss, off, 64);
    ss = __shfl(ss, 0, 64);
    float inv = 1.0f / fmaxf(sqrtf(ss), EPS_);
    union { ushort_t u[8]; uint4 v; } o;
    o.u[0] = f2bf(a.x * inv); o.u[1] = f2bf(a.y * inv);
    o.u[2] = f2bf(a.z * inv); o.u[3] = f2bf(a.w * inv);
    o.u[4] = f2bf(b.x * inv); o.u[5] = f2bf(b.y * inv);
    o.u[6] = f2bf(b.z * inv); o.u[7] = f2bf(b.w * inv);
    ((uint4*)(out + (size_t)row * 512))[lane] = o.v;
}

// ---------------- bf16 MFMA GEMM: out[M,N] = S * A[M,K] @ Bw[N,K]^T ----------
// 128x128 tile, BK=32, 4 waves each computing 64x64 via 4x4 of 16x16x32 MFMA.
__global__ __launch_bounds__(256) void gemm_bf16(const ushort_t* __restrict__ A,
                                                 const ushort_t* __restrict__ Bw,
                                                 float* __restrict__ out,
                                                 int M, int N, int K) {
    __shared__ ushort_t lA[128 * 32];
    __shared__ ushort_t lB[128 * 32];
    int tid  = threadIdx.x;
    int wave = tid >> 6, lane = tid & 63;
    int quad = lane >> 4, l16 = lane & 15;
    int bm = blockIdx.x, bn = blockIdx.y;

    f32x4 acc[4][4];
    #pragma unroll
    for (int mt = 0; mt < 4; mt++)
        #pragma unroll
        for (int nt = 0; nt < 4; nt++)
            acc[mt][nt] = (f32x4){0.f, 0.f, 0.f, 0.f};

    // staging addresses: thread t fills LDS bytes [t*16, t*16+16)
    int arow0 = bm * 128 + (tid >> 2);
    int br0 = bn * 128 + (tid >> 2);        if (br0 > N - 1) br0 = N - 1;
    int br1 = bn * 128 + 64 + (tid >> 2);   if (br1 > N - 1) br1 = N - 1;
    const ushort_t* ag0 = A  + (size_t)arow0 * K + (tid & 3) * 8;
    const ushort_t* ag1 = ag0 + (size_t)64 * K;
    const ushort_t* bg0 = Bw + (size_t)br0 * K + (tid & 3) * 8;
    const ushort_t* bg1 = Bw + (size_t)br1 * K + (tid & 3) * 8;

    // wave-uniform LDS bases (HW adds lane*16 bytes)
    ushort_t* lA0 = lA + wave * 512;
    ushort_t* lA1 = lA + 2048 + wave * 512;
    ushort_t* lB0 = lB + wave * 512;
    ushort_t* lB1 = lB + 2048 + wave * 512;

    // fragment read bases: A[m=l16][k=quad*8+j], B[n=l16][k=quad*8+j]
    const ushort_t* aBase = lA + ((size_t)((wave >> 1) * 64 + l16)) * 32 + quad * 8;
    const ushort_t* bBase = lB + ((size_t)((wave & 1) * 64 + l16)) * 32 + quad * 8;

    for (int k0 = 0; k0 < K; k0 += 32) {
        if (k0) __syncthreads();
        __builtin_amdgcn_global_load_lds((const __attribute__((address_space(1))) void*)(ag0 + k0),
                                         (__attribute__((address_space(3))) void*)lA0, 16, 0, 0);
        __builtin_amdgcn_global_load_lds((const __attribute__((address_space(1))) void*)(ag1 + k0),
                                         (__attribute__((address_space(3))) void*)lA1, 16, 0, 0);
        __builtin_amdgcn_global_load_lds((const __attribute__((address_space(1))) void*)(bg0 + k0),
                                         (__attribute__((address_space(3))) void*)lB0, 16, 0, 0);
        __builtin_amdgcn_global_load_lds((const __attribute__((address_space(1))) void*)(bg1 + k0),
                                         (__attribute__((address_space(3))) void*)lB1, 16, 0, 0);
        __syncthreads();

        bf16x8 af[4], bf[4];
        #pragma unroll
        for (int mt = 0; mt < 4; mt++) af[mt] = *(const bf16x8*)(aBase + mt * 16 * 32);
        #pragma unroll
        for (int nt = 0; nt < 4; nt++) bf[nt] = *(const bf16x8*)(bBase + nt * 16 * 32);
        #pragma unroll
        for (int mt = 0; mt < 4; mt++)
            #pragma unroll
            for (int nt = 0; nt < 4; nt++)
                acc[mt][nt] = __builtin_amdgcn_mfma_f32_16x16x32_bf16(af[mt], bf[nt], acc[mt][nt], 0, 0, 0);
    }

    // epilogue: C/D layout col=lane&15, row=quad*4+reg
    int row0 = bm * 128 + (wave >> 1) * 64 + quad * 4;
    int col0 = bn * 128 + (wave & 1) * 64 + l16;
    #pragma unroll
    for (int mt = 0; mt < 4; mt++) {
        #pragma unroll
        for (int nt = 0; nt < 4; nt++) {
            int c = col0 + nt * 16;
            if (c < N) {
                #pragma unroll
                for (int r = 0; r < 4; r++) {
                    out[(size_t)(row0 + mt * 16 + r) * N + c] = acc[mt][nt][r] * SSCALE;
                }
            }
        }
    }
}

// ---------------- fixup: apply arcface margin at (i, label[i]) ---------------
__global__ void fixup_kernel(const int* __restrict__ label, float* __restrict__ out,
                             int Bsz, int C) {
    int i = blockIdx.x * blockDim.x + threadIdx.x;
    if (i >= Bsz) return;
    int j = label[i];
    size_t idx = (size_t)i * C + j;
    float cosv = out[idx] * (1.0f / SSCALE);
    float sinv = sqrtf(fmaxf(0.f, 1.f - cosv * cosv));
    float phi = cosv * COSM_ - sinv * SINM_;
    if (!(cosv > TH_)) phi = cosv - MM_;
    out[idx] = phi * SSCALE;
}

// ---------------- fallback path (if workspace too small for bf16 copies) ----
__global__ __launch_bounds__(256) void rownorm_inv(const float* __restrict__ in,
                                                   float* __restrict__ invn, int nrows) {
    int row = blockIdx.x * 4 + (threadIdx.x >> 6);
    if (row >= nrows) return;
    int lane = threadIdx.x & 63;
    const float4* p = (const float4*)(in + (size_t)row * 512);
    float4 a = p[2 * lane];
    float4 b = p[2 * lane + 1];
    float ss = a.x*a.x + a.y*a.y + a.z*a.z + a.w*a.w
             + b.x*b.x + b.y*b.y + b.z*b.z + b.w*b.w;
    #pragma unroll
    for (int off = 32; off > 0; off >>= 1) ss += __shfl_down(ss, off, 64);
    if (lane == 0) invn[row] = 1.0f / fmaxf(sqrtf(ss), EPS_);
}

__global__ __launch_bounds__(256) void naive_gemm(const float* __restrict__ x,
                                                  const float* __restrict__ w,
                                                  const float* __restrict__ invx,
                                                  const float* __restrict__ invw,
                                                  float* __restrict__ out, int Bsz, int C) {
    __shared__ float xs[512];
    int i = blockIdx.y;
    int j = blockIdx.x * 256 + threadIdx.x;
    for (int k = threadIdx.x; k < 512; k += 256) xs[k] = x[(size_t)i * 512 + k];
    __syncthreads();
    if (j >= C) return;
    const float* wr = w + (size_t)j * 512;
    float acc = 0.f;
    for (int k = 0; k < 512; k++) acc += xs[k] * wr[k];
    out[(size_t)i * C + j] = acc * invx[i] * invw[j] * SSCALE;
}

extern "C" void kernel_launch(void* const* d_in, const int* in_sizes, int n_in,
                              void* d_out, int out_size, void* d_ws, size_t ws_size,
                              hipStream_t stream) {
    const float* x = (const float*)d_in[0];
    const float* w = (const float*)d_in[1];
    const int* label = (const int*)d_in[2];
    float* out = (float*)d_out;

    const int Bsz = in_sizes[2];            // 512
    const int D   = 512;
    const int C   = in_sizes[1] / D;        // 100000

    size_t need = ((size_t)Bsz * D + (size_t)C * D) * sizeof(ushort_t);
    if (ws_size >= need) {
        ushort_t* xn = (ushort_t*)d_ws;
        ushort_t* wn = xn + (size_t)Bsz * D;
        norm_rows_bf16<<<(Bsz + 3) / 4, 256, 0, stream>>>(x, xn, Bsz);
        norm_rows_bf16<<<(C + 3) / 4, 256, 0, stream>>>(w, wn, C);
        dim3 grid(Bsz / 128, (C + 127) / 128);   // m fastest -> B-tile L2 reuse
        gemm_bf16<<<grid, 256, 0, stream>>>(xn, wn, out, Bsz, C, D);
    } else {
        float* invx = (float*)d_ws;
        float* invw = invx + Bsz;
        rownorm_inv<<<(Bsz + 3) / 4, 256, 0, stream>>>(x, invx, Bsz);
        rownorm_inv<<<(C + 3) / 4, 256, 0, stream>>>(w, invw, C);
        dim3 g((C + 255) / 256, Bsz);
        naive_gemm<<<g, 256, 0, stream>>>(x, w, invx, invw, out, Bsz, C);
    }
    fixup_kernel<<<(Bsz + 255) / 256, 256, 0, stream>>>(label, out, Bsz, C);
}

// Round 2
// 415.683 us; speedup vs baseline: 1.0611x; 1.0611x over previous
//
#include <hip/hip_runtime.h>
#include <cstdint>
#include <cstddef>

// ArcFace FC: out[i][j] = S * (j==label[i] ? phi(cos_ij) : cos_ij)
// cos = normalize(x) @ normalize(W)^T,  B=512, D=512, C=100000

#define SSCALE 30.0f
#define COSM_  0.8775825618903728f
#define SINM_  0.4794255386042030f
#define TH_    (-0.8775825618903728f)
#define MM_    0.2397127693021015f
#define EPS_   1e-12f

typedef unsigned short ushort_t;
typedef __attribute__((ext_vector_type(8))) short bf16x8;
typedef __attribute__((ext_vector_type(16))) float f32x16;

__device__ inline ushort_t f2bf(float f) {
    union { float f; unsigned u; } x; x.f = f;
    unsigned r = (x.u + 0x7fffu + ((x.u >> 16) & 1u)) >> 16;
    return (ushort_t)r;
}

// ---------------- normalize rows (D=512) fp32 -> bf16, x and W in one launch
// one wave per row; fully coalesced: lane reads float4 at [lane] and [lane+64]
__global__ __launch_bounds__(256) void norm_all_bf16(const float* __restrict__ x,
                                                     const float* __restrict__ w,
                                                     ushort_t* __restrict__ xn,
                                                     ushort_t* __restrict__ wn,
                                                     int C, int Bsz) {
    int rowg = blockIdx.x * 4 + (threadIdx.x >> 6);
    if (rowg >= C + Bsz) return;
    int lane = threadIdx.x & 63;
    const float* src;
    ushort_t* dst;
    if (rowg < C) { src = w + (size_t)rowg * 512; dst = wn + (size_t)rowg * 512; }
    else          { src = x + (size_t)(rowg - C) * 512; dst = xn + (size_t)(rowg - C) * 512; }
    float4 a = ((const float4*)src)[lane];
    float4 b = ((const float4*)src)[lane + 64];
    float ss = a.x*a.x + a.y*a.y + a.z*a.z + a.w*a.w
             + b.x*b.x + b.y*b.y + b.z*b.z + b.w*b.w;
    #pragma unroll
    for (int off = 32; off > 0; off >>= 1) ss += __shfl_down(ss, off, 64);
    ss = __shfl(ss, 0, 64);
    float inv = 1.0f / fmaxf(sqrtf(ss), EPS_);
    union { ushort_t u[4]; uint2 v; } oa, ob;
    oa.u[0] = f2bf(a.x * inv); oa.u[1] = f2bf(a.y * inv);
    oa.u[2] = f2bf(a.z * inv); oa.u[3] = f2bf(a.w * inv);
    ob.u[0] = f2bf(b.x * inv); ob.u[1] = f2bf(b.y * inv);
    ob.u[2] = f2bf(b.z * inv); ob.u[3] = f2bf(b.w * inv);
    ((uint2*)dst)[lane]      = oa.v;
    ((uint2*)dst)[lane + 64] = ob.v;
}

// ---------------- bf16 MFMA GEMM: out[M,N] = S * A[M,K] @ Bw[N,K]^T ----------
// 128x128 tile, BK=32, 4 waves each 64x64 via 2x2 of 32x32x16 MFMA (2 k-steps).
// LDS layout (per operand): 128 rows x 4 chunks of 16B, chunk XOR-swizzled by
// (row>>1)&3 so the 32x32 fragment ds_read_b128 hits all 32 banks (8/bank).
// global_load_lds realizes the swizzle for free: each thread picks its source.
__global__ __launch_bounds__(256) void gemm_bf16(const ushort_t* __restrict__ A,
                                                 const ushort_t* __restrict__ Bw,
                                                 float* __restrict__ out,
                                                 int M, int N, int K) {
    __shared__ ushort_t lA[128 * 32];
    __shared__ ushort_t lB[128 * 32];
    int tid  = threadIdx.x;
    int wave = tid >> 6, lane = tid & 63;
    int half = lane >> 5, n5 = lane & 31;
    int bm = blockIdx.x, bn = blockIdx.y;

    f32x16 acc[2][2];
    #pragma unroll
    for (int mt = 0; mt < 2; mt++)
        #pragma unroll
        for (int nt = 0; nt < 2; nt++)
            #pragma unroll
            for (int r = 0; r < 16; r++)
                acc[mt][nt][r] = 0.f;

    // staging: thread t owns 16B slot t (call 1) and t+256 (call 2).
    // slot = row*4 + (chunk ^ ((row>>1)&3));  row = t>>2 (+64 for call 2),
    // chunk c0 = (t&3) ^ ((t>>3)&3)  (identical for both calls).
    int srow = tid >> 2;
    int c0   = (tid & 3) ^ ((tid >> 3) & 3);
    int arow = bm * 128 + srow;
    int br0 = bn * 128 + srow;        if (br0 > N - 1) br0 = N - 1;
    int br1 = bn * 128 + 64 + srow;   if (br1 > N - 1) br1 = N - 1;
    const ushort_t* ag0 = A  + (size_t)arow * K + c0 * 8;
    const ushort_t* ag1 = ag0 + (size_t)64 * K;
    const ushort_t* bg0 = Bw + (size_t)br0 * K + c0 * 8;
    const ushort_t* bg1 = Bw + (size_t)br1 * K + c0 * 8;

    // wave-uniform LDS bases (HW adds lane*16 bytes)
    ushort_t* lA0 = lA + wave * 512;
    ushort_t* lA1 = lA + 2048 + wave * 512;
    ushort_t* lB0 = lB + wave * 512;
    ushort_t* lB1 = lB + 2048 + wave * 512;

    // fragment read bases: A[m = mbase+n5][k = ks*16 + half*8 + j]
    // lds ushort idx = row*32 + (c ^ ((row>>1)&3))*8,  c = ks*2 + half
    int sw  = (n5 >> 1) & 3;             // (row>>1)&3 — row bases are mult of 32
    int cs0 = (half ^ sw) * 8;           // ks=0 chunk offset (ushorts)
    int cs1 = ((2 ^ half ^ sw)) * 8;     // ks=1
    const ushort_t* pArow = lA + ((wave >> 1) * 64 + n5) * 32;
    const ushort_t* pBrow = lB + ((wave & 1) * 64 + n5) * 32;

    for (int k0 = 0; k0 < K; k0 += 32) {
        if (k0) __syncthreads();
        __builtin_amdgcn_global_load_lds((const __attribute__((address_space(1))) void*)(ag0 + k0),
                                         (__attribute__((address_space(3))) void*)lA0, 16, 0, 0);
        __builtin_amdgcn_global_load_lds((const __attribute__((address_space(1))) void*)(ag1 + k0),
                                         (__attribute__((address_space(3))) void*)lA1, 16, 0, 0);
        __builtin_amdgcn_global_load_lds((const __attribute__((address_space(1))) void*)(bg0 + k0),
                                         (__attribute__((address_space(3))) void*)lB0, 16, 0, 0);
        __builtin_amdgcn_global_load_lds((const __attribute__((address_space(1))) void*)(bg1 + k0),
                                         (__attribute__((address_space(3))) void*)lB1, 16, 0, 0);
        __syncthreads();

        bf16x8 af[2][2], bf[2][2];
        #pragma unroll
        for (int mt = 0; mt < 2; mt++) {
            af[mt][0] = *(const bf16x8*)(pArow + mt * 1024 + cs0);
            af[mt][1] = *(const bf16x8*)(pArow + mt * 1024 + cs1);
        }
        #pragma unroll
        for (int nt = 0; nt < 2; nt++) {
            bf[nt][0] = *(const bf16x8*)(pBrow + nt * 1024 + cs0);
            bf[nt][1] = *(const bf16x8*)(pBrow + nt * 1024 + cs1);
        }
        #pragma unroll
        for (int ks = 0; ks < 2; ks++)
            #pragma unroll
            for (int mt = 0; mt < 2; mt++)
                #pragma unroll
                for (int nt = 0; nt < 2; nt++)
                    acc[mt][nt] = __builtin_amdgcn_mfma_f32_32x32x16_bf16(
                        af[mt][ks], bf[nt][ks], acc[mt][nt], 0, 0, 0);
    }

    // epilogue: 32x32 C/D layout col = lane&31, row = (reg&3) + 8*(reg>>2) + 4*half
    int row0 = bm * 128 + (wave >> 1) * 64 + 4 * half;
    int col0 = bn * 128 + (wave & 1) * 64 + n5;
    #pragma unroll
    for (int mt = 0; mt < 2; mt++) {
        #pragma unroll
        for (int nt = 0; nt < 2; nt++) {
            int c = col0 + nt * 32;
            if (c < N) {
                #pragma unroll
                for (int r = 0; r < 16; r++) {
                    int row = row0 + mt * 32 + (r & 3) + 8 * (r >> 2);
                    __builtin_nontemporal_store(acc[mt][nt][r] * SSCALE,
                                                &out[(size_t)row * N + c]);
                }
            }
        }
    }
}

// ---------------- fixup: apply arcface margin at (i, label[i]) ---------------
__global__ void fixup_kernel(const int* __restrict__ label, float* __restrict__ out,
                             int Bsz, int C) {
    int i = blockIdx.x * blockDim.x + threadIdx.x;
    if (i >= Bsz) return;
    int j = label[i];
    size_t idx = (size_t)i * C + j;
    float cosv = out[idx] * (1.0f / SSCALE);
    float sinv = sqrtf(fmaxf(0.f, 1.f - cosv * cosv));
    float phi = cosv * COSM_ - sinv * SINM_;
    if (!(cosv > TH_)) phi = cosv - MM_;
    out[idx] = phi * SSCALE;
}

// ---------------- fallback path (if workspace too small for bf16 copies) ----
__global__ __launch_bounds__(256) void rownorm_inv(const float* __restrict__ in,
                                                   float* __restrict__ invn, int nrows) {
    int row = blockIdx.x * 4 + (threadIdx.x >> 6);
    if (row >= nrows) return;
    int lane = threadIdx.x & 63;
    const float4* p = (const float4*)(in + (size_t)row * 512);
    float4 a = p[lane];
    float4 b = p[lane + 64];
    float ss = a.x*a.x + a.y*a.y + a.z*a.z + a.w*a.w
             + b.x*b.x + b.y*b.y + b.z*b.z + b.w*b.w;
    #pragma unroll
    for (int off = 32; off > 0; off >>= 1) ss += __shfl_down(ss, off, 64);
    if (lane == 0) invn[row] = 1.0f / fmaxf(sqrtf(ss), EPS_);
}

__global__ __launch_bounds__(256) void naive_gemm(const float* __restrict__ x,
                                                  const float* __restrict__ w,
                                                  const float* __restrict__ invx,
                                                  const float* __restrict__ invw,
                                                  float* __restrict__ out, int Bsz, int C) {
    __shared__ float xs[512];
    int i = blockIdx.y;
    int j = blockIdx.x * 256 + threadIdx.x;
    for (int k = threadIdx.x; k < 512; k += 256) xs[k] = x[(size_t)i * 512 + k];
    __syncthreads();
    if (j >= C) return;
    const float* wr = w + (size_t)j * 512;
    float acc = 0.f;
    for (int k = 0; k < 512; k++) acc += xs[k] * wr[k];
    out[(size_t)i * C + j] = acc * invx[i] * invw[j] * SSCALE;
}

extern "C" void kernel_launch(void* const* d_in, const int* in_sizes, int n_in,
                              void* d_out, int out_size, void* d_ws, size_t ws_size,
                              hipStream_t stream) {
    const float* x = (const float*)d_in[0];
    const float* w = (const float*)d_in[1];
    const int* label = (const int*)d_in[2];
    float* out = (float*)d_out;

    const int Bsz = in_sizes[2];            // 512
    const int D   = 512;
    const int C   = in_sizes[1] / D;        // 100000

    size_t need = ((size_t)Bsz * D + (size_t)C * D) * sizeof(ushort_t);
    if (ws_size >= need) {
        ushort_t* xn = (ushort_t*)d_ws;
        ushort_t* wn = xn + (size_t)Bsz * D;
        norm_all_bf16<<<(C + Bsz + 3) / 4, 256, 0, stream>>>(x, w, xn, wn, C, Bsz);
        dim3 grid(Bsz / 128, (C + 127) / 128);   // m fastest -> B-tile L2 reuse
        gemm_bf16<<<grid, 256, 0, stream>>>(xn, wn, out, Bsz, C, D);
    } else {
        float* invx = (float*)d_ws;
        float* invw = invx + Bsz;
        rownorm_inv<<<(Bsz + 3) / 4, 256, 0, stream>>>(x, invx, Bsz);
        rownorm_inv<<<(C + 3) / 4, 256, 0, stream>>>(w, invw, C);
        dim3 g((C + 255) / 256, Bsz);
        naive_gemm<<<g, 256, 0, stream>>>(x, w, invx, invw, out, Bsz, C);
    }
    fixup_kernel<<<(Bsz + 255) / 256, 256, 0, stream>>>(label, out, Bsz, C);
}